// Round 2
// baseline (354.993 us; speedup 1.0000x reference)
//
#include <hip/hip_runtime.h>
#include <hip/hip_fp16.h>
#include <math.h>

typedef _Float16 f16;
typedef unsigned int u32;
typedef _Float16 f16x8 __attribute__((ext_vector_type(8)));
typedef _Float16 f16x4 __attribute__((ext_vector_type(4)));
typedef float    f32x4 __attribute__((ext_vector_type(4)));

constexpr int LEN  = 512;
constexpr int HID  = 512;
constexpr int BATCH = 64;

#define BM 128
#define BN 128
#define BK 64

// ---- async global->LDS, 16B per lane. lds ptr must be wave-uniform. ----
__device__ __forceinline__ void gload16(const f16* g, f16* l) {
    __builtin_amdgcn_global_load_lds((const __attribute__((address_space(1))) u32*)g,
                                     (__attribute__((address_space(3))) u32*)l,
                                     16, 0, 0);
}

__device__ __forceinline__ float silu_f(float v) {
    return v * __builtin_amdgcn_rcpf(1.f + __expf(-v));
}

// ============================================================================
// 256x256 8-wave pipelined core, round 2.
//
// BK=32, K=512 -> 16 K-tiles. FOUR LDS stage buffers of 32KB: 3 tiles in
// flight (m201 depth). Steady-state end-of-iter wait = vmcnt(8): outstanding
// {kt+1,kt+2,kt+3}x4 loads, retire exactly tile kt+1. Tail: 8 -> 4 -> 0.
//
// Swizzle fix vs round 1: bank 16B-position = (row&1)<<2 | slot. Old slot
// key (row&3) repeated every 4 rows -> 4-way conflict (4.19e6 measured).
// New: slot = chunk ^ ((row>>1)&3); 16 frag rows cover all 8 positions
// exactly twice -> 2-way = free (m136). Applied BOTH sides (rule 21):
// inverse-permuted global source chunk + same XOR on ds_read address.
// ============================================================================
#define LDSP 272   // epilogue store pitch (544B stride, 16B-aligned)

__device__ __forceinline__ void stage_pass8(const f16* __restrict__ g, f16* l) {
    const int tid = threadIdx.x;
    const int row = tid >> 2;                         // 0..127
    const int sc  = (tid & 3) ^ ((row >> 1) & 3);     // inverse-swizzled chunk
    gload16(g + (size_t)row * HID + sc * 8, l + (tid >> 6) * 512);
}

__device__ __forceinline__ void stage_tile8(const f16* __restrict__ A,
                                            const f16* __restrict__ B,
                                            int kt, f16* buf) {
    stage_pass8(A + kt * 32,             buf);
    stage_pass8(A + kt * 32 + 128 * HID, buf + 4096);
    stage_pass8(B + kt * 32,             buf + 8192);
    stage_pass8(B + kt * 32 + 128 * HID, buf + 12288);
}

// acc[8][4]: wave (wr,wc) owns rows wr*128..+127, cols wc*64..+63.
__device__ __forceinline__ void gemm8_core(const f16* __restrict__ A,
                                           const f16* __restrict__ B,
                                           f16* lds, f32x4 acc[8][4])
{
    const int tid  = threadIdx.x;
    const int lane = tid & 63;
    const int wv   = tid >> 6;
    const int wr   = wv >> 2, wc = wv & 3;
    const int mf   = lane & 15;
    const int slot = ((lane >> 4) ^ ((mf >> 1) & 3)) * 8;   // (row>>1)&3 == (mf>>1)&3
    const int aoff = (wr * 128 + mf) * 32 + slot;
    const int boff = (wc * 64  + mf) * 32 + slot + 8192;

    #pragma unroll
    for (int m = 0; m < 8; ++m)
        #pragma unroll
        for (int n = 0; n < 4; ++n)
            acc[m][n] = (f32x4){0.f, 0.f, 0.f, 0.f};

    // prologue: 3 tiles in flight; retire tile 0 only (12 issued, wait to 8).
    stage_tile8(A, B, 0, lds);
    stage_tile8(A, B, 1, lds + 16384);
    stage_tile8(A, B, 2, lds + 32768);
    asm volatile("s_waitcnt vmcnt(8)" ::: "memory");
    __builtin_amdgcn_s_barrier();

    f16x8 af[4], bf[4];
    #pragma unroll
    for (int kt = 0; kt < 16; ++kt) {
        f16* buf  = lds + (kt & 3) * 16384;
        f16* nbuf = lds + ((kt + 3) & 3) * 16384;
        const bool st = (kt < 13);

        // ---- phase A: frags m0-3 x n0-3, stage A-halves of tile kt+3 ----
        #pragma unroll
        for (int m = 0; m < 4; ++m) af[m] = *(const f16x8*)(buf + aoff + m * 512);
        #pragma unroll
        for (int n = 0; n < 4; ++n) bf[n] = *(const f16x8*)(buf + boff + n * 512);
        if (st) {
            stage_pass8(A + (kt + 3) * 32,             nbuf);
            stage_pass8(A + (kt + 3) * 32 + 128 * HID, nbuf + 4096);
        }
        __builtin_amdgcn_s_barrier();
        asm volatile("s_waitcnt lgkmcnt(0)" ::: "memory");
        __builtin_amdgcn_sched_barrier(0);
        __builtin_amdgcn_s_setprio(1);
        #pragma unroll
        for (int m = 0; m < 4; ++m)
            #pragma unroll
            for (int n = 0; n < 4; ++n)
                acc[m][n] = __builtin_amdgcn_mfma_f32_16x16x32_f16(af[m], bf[n], acc[m][n], 0, 0, 0);
        __builtin_amdgcn_s_setprio(0);
        __builtin_amdgcn_s_barrier();

        // ---- phase B: frags m4-7 x n0-3 (reuse bf), stage B-halves ----
        #pragma unroll
        for (int m = 0; m < 4; ++m) af[m] = *(const f16x8*)(buf + aoff + (m + 4) * 512);
        if (st) {
            stage_pass8(B + (kt + 3) * 32,             nbuf + 8192);
            stage_pass8(B + (kt + 3) * 32 + 128 * HID, nbuf + 12288);
        }
        __builtin_amdgcn_s_barrier();
        asm volatile("s_waitcnt lgkmcnt(0)" ::: "memory");
        __builtin_amdgcn_sched_barrier(0);
        __builtin_amdgcn_s_setprio(1);
        #pragma unroll
        for (int m = 0; m < 4; ++m)
            #pragma unroll
            for (int n = 0; n < 4; ++n)
                acc[m + 4][n] = __builtin_amdgcn_mfma_f32_16x16x32_f16(af[m], bf[n], acc[m + 4][n], 0, 0, 0);
        __builtin_amdgcn_s_setprio(0);
        if (kt < 13)       asm volatile("s_waitcnt vmcnt(8)" ::: "memory");
        else if (kt == 13) asm volatile("s_waitcnt vmcnt(4)" ::: "memory");
        else if (kt == 14) asm volatile("s_waitcnt vmcnt(0)" ::: "memory");
        __builtin_amdgcn_s_barrier();
    }
}

#define EPI8_IDX() \
    const int lane = threadIdx.x & 63, wv_ = threadIdx.x >> 6;  \
    const int wr = wv_ >> 2, wc = wv_ & 3;                      \
    const int c0 = lane & 15, r0 = (lane >> 4) * 4;

// store half-tile h (global rows h*128..+127) from lds[128][LDSP]
__device__ __forceinline__ void store_half8(const f16* lds, f16* __restrict__ gout,
                                            int ldo, int h) {
    const int tid = threadIdx.x;
    #pragma unroll
    for (int ph = 0; ph < 8; ++ph) {
        const int r = ph * 16 + (tid >> 5);
        const int c = (tid & 31) * 8;
        *(f16x8*)(gout + (size_t)(h * 128 + r) * ldo + c) = *(const f16x8*)(lds + r * LDSP + c);
    }
}

// ---- fused z | v^T, 256^2 tiles, XCD-grouped: slab s's 4 consumers share bid%8 ----
// 512 blocks: bid = (s&7) + 8*ci + 32*(s>>3); ci<2: z nt=ci; ci>=2: vt ht=ci-2
__global__ __launch_bounds__(512, 2) void k_zv8(const f16* __restrict__ x,
                                                const f16* __restrict__ Wzh,
                                                const f16* __restrict__ Wvh,
                                                f16* __restrict__ z,
                                                f16* __restrict__ vt)
{
    __shared__ __align__(16) f16 lds[65536];       // 128 KB: 4 stage bufs / epilogue
    const int bid = blockIdx.x;
    const int s  = (bid & 7) + 8 * (bid >> 5);     // x-slab 0..127 (256 rows each)
    const int ci = (bid >> 3) & 3;
    const f16* A; const f16* Bm; f16* gout;
    if (ci < 2) {                                  // z[s, nt=ci] = silu(x_s @ Wz_nt^T)
        A = x + (size_t)s * 256 * HID;
        Bm = Wzh + (size_t)ci * 256 * HID;
        gout = z + (size_t)s * 256 * HID + ci * 256;
    } else {                                       // vt[b, ht, mt] = silu(Wv_ht @ x^T)
        const int ht = ci - 2, b = s >> 1, mt = s & 1;
        A = Wvh + (size_t)ht * 256 * HID;
        Bm = x + ((size_t)b * LEN + mt * 256) * HID;
        gout = vt + (size_t)b * HID * LEN + (size_t)ht * 256 * LEN + mt * 256;
    }
    f32x4 acc[8][4];
    gemm8_core(A, Bm, lds, acc);
    EPI8_IDX();
    #pragma unroll
    for (int h = 0; h < 2; ++h) {
        if (wr == h) {
            #pragma unroll
            for (int m = 0; m < 8; ++m)
                #pragma unroll
                for (int n = 0; n < 4; ++n)
                    #pragma unroll
                    for (int i = 0; i < 4; ++i) {
                        const int row = m * 16 + r0 + i;           // 0..127 local
                        const int col = wc * 64 + n * 16 + c0;
                        lds[row * LDSP + col] = (f16)silu_f(acc[m][n][i]);
                    }
        }
        __syncthreads();
        store_half8(lds, gout, 512, h);
        __syncthreads();
    }
}

// ---- fused q | k projections, same structure over z-slabs ----
__global__ __launch_bounds__(512, 2) void k_qkp8(const f16* __restrict__ z,
                                                 const f16* __restrict__ Wqh,
                                                 const f16* __restrict__ Wkh,
                                                 const float* __restrict__ gq,
                                                 const float* __restrict__ bq,
                                                 const float* __restrict__ gk,
                                                 const float* __restrict__ bk,
                                                 f16* __restrict__ qh,
                                                 f16* __restrict__ kh)
{
    __shared__ __align__(16) f16 lds[65536];
    const int bid = blockIdx.x;
    const int s  = (bid & 7) + 8 * (bid >> 5);
    const int ci = (bid >> 3) & 3;
    const bool isq = ci < 2;
    const int nt = isq ? ci : ci - 2;
    const f16* W = isq ? Wqh : Wkh;
    const float* g  = isq ? gq : gk;
    const float* be = isq ? bq : bk;
    f16* outp = isq ? qh : kh;
    f32x4 acc[8][4];
    gemm8_core(z + (size_t)s * 256 * HID, W + (size_t)nt * 256 * HID, lds, acc);
    EPI8_IDX();
    f16* gbase = outp + (size_t)s * 256 * HID + nt * 256;
    #pragma unroll
    for (int h = 0; h < 2; ++h) {
        if (wr == h) {
            #pragma unroll
            for (int n = 0; n < 4; ++n) {
                const int col = wc * 64 + n * 16 + c0;
                const int jg = nt * 256 + col;
                const float ga = g[jg], ba = be[jg];
                #pragma unroll
                for (int m = 0; m < 8; ++m)
                    #pragma unroll
                    for (int i = 0; i < 4; ++i) {
                        const int row = m * 16 + r0 + i;
                        lds[row * LDSP + col] = (f16)((acc[m][n][i] * ga + ba) * 1024.f);
                    }
            }
        }
        __syncthreads();
        store_half8(lds, gbase, 512, h);
        __syncthreads();
    }
}

// ============================================================================
// legacy 128^2 core (k_qk / k_pv)
// ============================================================================
__device__ __forceinline__ void gemm_core(const f16* __restrict__ A, int lda,
                                          const f16* __restrict__ Bm, int ldb,
                                          int ksteps,
                                          f16* ldsA, f16* ldsB,
                                          f32x4 acc[4][4])
{
    const int tid  = threadIdx.x;
    const int lane = tid & 63;
    const int wv   = tid >> 6;
    const int wr   = wv >> 1, wc = wv & 1;
    const int mf   = lane & 15;
    const int kf   = (lane >> 4) * 8;

    for (int r = 0; r < 4; ++r)
        for (int c = 0; c < 4; ++c)
            acc[r][c] = (f32x4){0.f, 0.f, 0.f, 0.f};

    for (int kt = 0; kt < ksteps; ++kt) {
        const int k0 = kt * BK;
        #pragma unroll
        for (int j = 0; j < 4; ++j) {
            const int cb  = j * 256 + wv * 64;
            const int c   = cb + lane;
            const int row = c >> 3;
            const int col = (c & 7) << 3;
            gload16(A  + (size_t)row * lda + (k0 + col), ldsA + cb * 8);
            gload16(Bm + (size_t)row * ldb + (k0 + col), ldsB + cb * 8);
        }
        __syncthreads();
        #pragma unroll
        for (int kk = 0; kk < BK; kk += 32) {
            f16x8 af[4], bf[4];
            #pragma unroll
            for (int r = 0; r < 4; ++r) {
                af[r] = *(const f16x8*)(ldsA + (wr * 64 + r * 16 + mf) * BK + kk + kf);
                bf[r] = *(const f16x8*)(ldsB + (wc * 64 + r * 16 + mf) * BK + kk + kf);
            }
            #pragma unroll
            for (int r = 0; r < 4; ++r)
                #pragma unroll
                for (int c = 0; c < 4; ++c)
                    acc[r][c] = __builtin_amdgcn_mfma_f32_16x16x32_f16(af[r], bf[c], acc[r][c], 0, 0, 0);
        }
        __syncthreads();
    }
}

// C/D layout (16x16x32): col = lane&15, row = (lane>>4)*4 + reg   [m89-verified]
#define EPILOGUE_IDX() \
    const int lane = threadIdx.x & 63, wv_ = threadIdx.x >> 6;   \
    const int wr = wv_ >> 1, wc = wv_ & 1;                       \
    const int c0 = lane & 15, r0 = (lane >> 4) * 4;

__device__ __forceinline__ void store_tile_f16(f16* lds, const f16 vals[4][4][4],
                                               f16* __restrict__ gout, int ldo)
{
    const int tid = threadIdx.x;
    EPILOGUE_IDX();
    #pragma unroll
    for (int r = 0; r < 4; ++r)
        #pragma unroll
        for (int c = 0; c < 4; ++c)
            #pragma unroll
            for (int i = 0; i < 4; ++i) {
                const int lr = wr * 64 + r * 16 + r0 + i;
                const int lc = wc * 64 + c * 16 + c0;
                lds[lr * 128 + lc] = vals[r][c][i];
            }
    __syncthreads();
    #pragma unroll
    for (int ph = 0; ph < 8; ++ph) {
        const int row = ph * 16 + (tid >> 4);
        const int col = (tid & 15) * 8;
        *(f16x8*)(gout + (size_t)row * ldo + col) = *(const f16x8*)(lds + row * 128 + col);
    }
}

// ---- batched q@k^T + mask + smask + relu^2 -> p, triangular, per-batch XCD ----
__constant__ int LT_TAB[10] = {0,1,1,2,2,2,3,3,3,3};
__constant__ int MT_TAB[10] = {0,0,1,0,1,2,0,1,2,3};

__global__ __launch_bounds__(256) void k_qk(const f16* __restrict__ q,
                                            const f16* __restrict__ kmat,
                                            const int* __restrict__ mask,
                                            const float* __restrict__ smask,
                                            f16* __restrict__ p)
{
    const int bid = blockIdx.x;
    const int t = (bid >> 3) % 10;
    const int b = (bid & 7) + 8 * (bid / 80);
    const int lt = LT_TAB[t], mt = MT_TAB[t];
    __shared__ f16 lds[(BM + BN) * BK];
    f32x4 acc[4][4];
    const size_t boff = (size_t)b * LEN * HID;
    gemm_core(q + boff + (size_t)lt * BM * HID, HID,
              kmat + boff + (size_t)mt * BN * HID, HID,
              HID / BK, lds, lds + BM * BK, acc);
    f16 vals[4][4][4];
    {
        EPILOGUE_IDX();
        #pragma unroll
        for (int r = 0; r < 4; ++r)
            #pragma unroll
            for (int c = 0; c < 4; ++c) {
                const int m = mt * BN + wc * 64 + c * 16 + c0;
                const int keepcol = mask[b * LEN + m];
                #pragma unroll
                for (int i = 0; i < 4; ++i) {
                    const int l = lt * BM + wr * 64 + r * 16 + r0 + i;
                    const bool keep = (l == m) || ((m <= l) && (keepcol != 0));
                    float v = keep ? acc[r][c][i] * smask[l * LEN + m] : 0.f;
                    v = fmaxf(v, 0.f);
                    vals[r][c][i] = (f16)(v * v);
                }
            }
    }
    store_tile_f16(lds, vals, p + (size_t)b * LEN * LEN + (size_t)lt * BM * LEN + mt * BN, LEN);
}

// ---- batched p@v -> out f32; causal K truncation; long lt first ----
__global__ __launch_bounds__(256) void k_pv(const f16* __restrict__ p,
                                            const f16* __restrict__ vt,
                                            float* __restrict__ out)
{
    const int bid = blockIdx.x;
    const int inner = (bid >> 3) & 15;
    const int b = (bid & 7) + 8 * (bid >> 7);
    const int lt = 3 - (inner >> 2), ht = inner & 3;
    __shared__ f16 lds[(BM + BN) * BK];
    f32x4 acc[4][4];
    gemm_core(p + (size_t)b * LEN * LEN + (size_t)lt * BM * LEN, LEN,
              vt + (size_t)b * HID * LEN + (size_t)ht * BN * LEN, LEN,
              (lt + 1) * BM / BK, lds, lds + BM * BK, acc);
    EPILOGUE_IDX();
    // undo q,k 2^10 lifts (squared -> 2^40) and /(L*H)=2^18 : 2^-58 exact
    const float SCALE = 3.4694469519536142e-18f;
    #pragma unroll
    for (int r = 0; r < 4; ++r)
        #pragma unroll
        for (int c = 0; c < 4; ++c) {
            const int h = ht * BN + wc * 64 + c * 16 + c0;
            #pragma unroll
            for (int i = 0; i < 4; ++i) {
                const int l = lt * BM + wr * 64 + r * 16 + r0 + i;
                out[(size_t)b * LEN * HID + (size_t)l * HID + h] = acc[r][c][i] * SCALE;
            }
        }
}

// ---- one prep launch: gather(x) + 4x weight f2h + smask ----
__global__ __launch_bounds__(256) void k_prep(const int* __restrict__ pos,
                                              const float* __restrict__ item_emb,
                                              const float* __restrict__ pos_emb,
                                              f16* __restrict__ x,
                                              const float* __restrict__ Wz,
                                              const float* __restrict__ Wv,
                                              const float* __restrict__ Wq,
                                              const float* __restrict__ Wk,
                                              f16* __restrict__ Wzh,
                                              f16* __restrict__ Wvh,
                                              f16* __restrict__ Wqh,
                                              f16* __restrict__ Wkh,
                                              const float* __restrict__ sw,
                                              const float* __restrict__ gum,
                                              float* __restrict__ smask)
{
    const int bid = blockIdx.x;
    const int tid = threadIdx.x;
    if (bid < 16384) {                       // gather: x = item_emb[pos] + pos_emb
        const int t = bid * 256 + tid;
        const int i = t >> 7;
        const int c = t & 127;
        const int l = i & (LEN - 1);
        const int item = pos[i];
        const float4 a  = ((const float4*)(item_emb + (size_t)item * HID))[c];
        const float4 b4 = ((const float4*)(pos_emb + (size_t)l * HID))[c];
        f16x4 o = { (f16)(a.x + b4.x), (f16)(a.y + b4.y),
                    (f16)(a.z + b4.z), (f16)(a.w + b4.w) };
        *(f16x4*)(x + (size_t)t * 4) = o;
    } else if (bid < 16384 + 1024) {         // weight f32 -> f16
        const int r = bid - 16384;
        const int w = r >> 8;
        const float* s = (w == 0) ? Wz : (w == 1) ? Wv : (w == 2) ? Wq : Wk;
        f16* d = (w == 0) ? Wzh : (w == 1) ? Wvh : (w == 2) ? Wqh : Wkh;
        const int t = (r & 255) * 256 + tid;
        const float4 v = ((const float4*)s)[t];
        f16x4 o = { (f16)v.x, (f16)v.y, (f16)v.z, (f16)v.w };
        *(f16x4*)(d + (size_t)t * 4) = o;
    } else {                                 // gumbel-sigmoid smask (fp32)
        const int t = (bid - 16384 - 1024) * 256 + tid;
        const float4 w4 = ((const float4*)sw)[t];
        const float4 g4 = ((const float4*)gum)[t];
        float4 o;
        o.x = __builtin_amdgcn_rcpf(1.f + __expf(-(__logf(w4.x / (1.f - w4.x)) + g4.x) * 5.f));
        o.y = __builtin_amdgcn_rcpf(1.f + __expf(-(__logf(w4.y / (1.f - w4.y)) + g4.y) * 5.f));
        o.z = __builtin_amdgcn_rcpf(1.f + __expf(-(__logf(w4.z / (1.f - w4.z)) + g4.z) * 5.f));
        o.w = __builtin_amdgcn_rcpf(1.f + __expf(-(__logf(w4.w / (1.f - w4.w)) + g4.w) * 5.f));
        ((float4*)smask)[t] = o;
    }
}

extern "C" void kernel_launch(void* const* d_in, const int* in_sizes, int n_in,
                              void* d_out, int out_size, void* d_ws, size_t ws_size,
                              hipStream_t stream)
{
    const int*   positives = (const int*)  d_in[0];
    const int*   mask      = (const int*)  d_in[1];
    const float* item_emb  = (const float*)d_in[2];
    const float* pos_emb   = (const float*)d_in[3];
    const float* Wz        = (const float*)d_in[4];
    const float* Wv        = (const float*)d_in[5];
    const float* Wq        = (const float*)d_in[6];
    const float* Wk        = (const float*)d_in[7];
    const float* gamma_q   = (const float*)d_in[8];
    const float* beta_q    = (const float*)d_in[9];
    const float* gamma_k   = (const float*)d_in[10];
    const float* beta_k    = (const float*)d_in[11];
    const float* sparse_w  = (const float*)d_in[12];
    const float* gumbel    = (const float*)d_in[13];
    float* out = (float*)d_out;

    char* ws = (char*)d_ws;
    const size_t BUFB = (size_t)BATCH * LEN * HID * sizeof(f16);  // 32 MB
    f16* buf0 = (f16*)ws;                // x  -> p
    f16* buf1 = (f16*)(ws + BUFB);       // z
    f16* buf2 = (f16*)(ws + 2 * BUFB);   // vt
    f16* Wzh  = (f16*)(ws + 3 * BUFB);
    f16* Wvh  = Wzh + LEN * HID;
    f16* Wqh  = Wvh + LEN * HID;
    f16* Wkh  = Wqh + LEN * HID;
    float* smask = (float*)(Wkh + LEN * HID);
    // q,k live in d_out (exactly 2 x 32MB fp16) until k_pv overwrites it
    f16* qh = (f16*)d_out;
    f16* kh = qh + (size_t)BATCH * LEN * HID;

    k_prep<<<16384 + 1024 + 256, 256, 0, stream>>>(
        positives, item_emb, pos_emb, buf0,
        Wz, Wv, Wq, Wk, Wzh, Wvh, Wqh, Wkh,
        sparse_w, gumbel, smask);

    k_zv8<<<512, 512, 0, stream>>>(buf0, Wzh, Wvh, buf1, buf2);

    k_qkp8<<<512, 512, 0, stream>>>(buf1, Wqh, Wkh,
                                    gamma_q, beta_q, gamma_k, beta_k, qh, kh);

    k_qk<<<640, 256, 0, stream>>>(qh, kh, mask, smask, buf0);

    k_pv<<<1024, 256, 0, stream>>>(buf0, buf2, out);
}

// Round 3
// 344.085 us; speedup vs baseline: 1.0317x; 1.0317x over previous
//
#include <hip/hip_runtime.h>
#include <hip/hip_fp16.h>
#include <math.h>

typedef _Float16 f16;
typedef unsigned int u32;
typedef _Float16 f16x8 __attribute__((ext_vector_type(8)));
typedef _Float16 f16x4 __attribute__((ext_vector_type(4)));
typedef float    f32x4 __attribute__((ext_vector_type(4)));

constexpr int LEN  = 512;
constexpr int HID  = 512;
constexpr int BATCH = 64;

// ---- async global->LDS, 16B per lane. lds ptr must be wave-uniform. ----
__device__ __forceinline__ void gload16(const f16* g, f16* l) {
    __builtin_amdgcn_global_load_lds((const __attribute__((address_space(1))) u32*)g,
                                     (__attribute__((address_space(3))) u32*)l,
                                     16, 0, 0);
}

__device__ __forceinline__ float silu_f(float v) {
    return v * __builtin_amdgcn_rcpf(1.f + __expf(-v));
}

// ============================================================================
// 256x128 8-wave core, BK=32, 3 stage bufs (72KB) -> 2 blocks/CU.
//
// Rationale (round-3): K=512 is a SHORT K-loop (16 tiles). At 1 block/CU the
// per-block prologue fill + 128KB epilogue store are fully exposed (LDS frees
// only at block exit). 72KB LDS + VGPR<=128 (launch_bounds(512,4)) gives 2
// resident blocks: block N+1's K-loop hides block N's epilogue/prologue.
//
// Pipeline: 2-ahead counted vmcnt. 3 loads/tile (A 256x32 = 2 passes,
// B 128x32 = 1 pass). Steady state: issue tile kt+2 during iter kt, end-of-
// iter s_waitcnt vmcnt(3) retires exactly tile kt+1 (outstanding = kt+1:3 +
// kt+2:3). Drains to 0 only at kt==ksteps-2. ONE barrier per iter: with 3
// buffers, buf being staged (kt+2) was last read at iter kt-1, and that
// iter's reads completed before its end-of-iter barrier -> race-free.
//
// LDS chunk swizzle (both sides, rule 21): row = 64B = 4 chunks of 16B.
// gload dest is linear; global source chunk = (tid&3) ^ ((row>>1)&3); read
// XORs the same key. 16B-position = (row&1)<<2 | slot: a 16-row fragment
// group covers all 8 positions exactly twice -> 2-way = free (m136).
// ============================================================================
#define TUNIT 12288   // f16 per K-tile buffer: A 256x32 (8192) + B 128x32 (4096)
#define EPIP  136     // epilogue pitch (272B/row = 4-bank rotate, 16B-aligned)

__device__ __forceinline__ void stage_pass(const f16* __restrict__ g, f16* l) {
    const int tid = threadIdx.x;
    const int row = tid >> 2;                       // 0..127
    const int sc  = (tid & 3) ^ ((row >> 1) & 3);   // inverse-swizzled chunk
    gload16(g + (size_t)row * 512 + sc * 8, l + (tid >> 6) * 512);
}

__device__ __forceinline__ void stage_tile(const f16* __restrict__ A,
                                           const f16* __restrict__ B,
                                           int kt, f16* buf) {
    stage_pass(A + kt * 32,             buf);            // A rows   0..127
    stage_pass(A + kt * 32 + 128 * 512, buf + 4096);     // A rows 128..255
    stage_pass(B + kt * 32,             buf + 8192);     // B rows   0..127
}

// acc[4][4]: wave (wr,wc): rows wr*64..+63, cols wc*64..+63 of the 256x128 tile
__device__ __forceinline__ void gemm8b(const f16* __restrict__ A,
                                       const f16* __restrict__ B,
                                       int ksteps, f16* lds, f32x4 acc[4][4])
{
    const int lane = threadIdx.x & 63;
    const int wv   = threadIdx.x >> 6;
    const int wr = wv >> 1, wc = wv & 1;
    const int mf = lane & 15;
    const int slot = ((lane >> 4) ^ ((mf >> 1) & 3)) * 8;   // (row>>1)&3 == (mf>>1)&3
    const int aoff = (wr * 64 + mf) * 32 + slot;
    const int boff = (wc * 64 + mf) * 32 + slot + 8192;

    #pragma unroll
    for (int m = 0; m < 4; ++m)
        #pragma unroll
        for (int n = 0; n < 4; ++n)
            acc[m][n] = (f32x4){0.f, 0.f, 0.f, 0.f};

    stage_tile(A, B, 0, lds);
    stage_tile(A, B, 1, lds + TUNIT);
    asm volatile("s_waitcnt vmcnt(3)" ::: "memory");   // tile0 retired, tile1 in flight
    __builtin_amdgcn_s_barrier();

    int cb = 0;
    for (int kt = 0; kt < ksteps; ++kt) {
        f16* buf = lds + cb * TUNIT;
        f16x8 af[4], bf[4];
        #pragma unroll
        for (int m = 0; m < 4; ++m) af[m] = *(const f16x8*)(buf + aoff + m * 512);
        #pragma unroll
        for (int n = 0; n < 4; ++n) bf[n] = *(const f16x8*)(buf + boff + n * 512);
        if (kt + 2 < ksteps) {
            int nb = cb + 2; if (nb >= 3) nb -= 3;
            stage_tile(A, B, kt + 2, lds + nb * TUNIT);
        }
        asm volatile("s_waitcnt lgkmcnt(0)" ::: "memory");
        __builtin_amdgcn_sched_barrier(0);
        __builtin_amdgcn_s_setprio(1);
        #pragma unroll
        for (int m = 0; m < 4; ++m)
            #pragma unroll
            for (int n = 0; n < 4; ++n)
                acc[m][n] = __builtin_amdgcn_mfma_f32_16x16x32_f16(af[m], bf[n], acc[m][n], 0, 0, 0);
        __builtin_amdgcn_s_setprio(0);
        if (kt + 3 <= ksteps) {                  // kt <= ksteps-3: tile kt+1 ready
            asm volatile("s_waitcnt vmcnt(3)" ::: "memory");
            __builtin_amdgcn_s_barrier();
        } else if (kt + 2 == ksteps) {           // last prefetched tile
            asm volatile("s_waitcnt vmcnt(0)" ::: "memory");
            __builtin_amdgcn_s_barrier();
        }
        cb = cb + 1; if (cb >= 3) cb = 0;
    }
}

// C/D layout (16x16x32): col = lane&15, row = (lane>>4)*4 + reg   [m89-verified]
#define EPI_IDX() \
    const int lane = threadIdx.x & 63, wv_ = threadIdx.x >> 6;  \
    const int wr = wv_ >> 1, wc = wv_ & 1;                      \
    const int c0 = lane & 15, r0 = (lane >> 4) * 4;

// coalesced copy of half-tile h (rows h*128..+127) from lds[128][EPIP]
__device__ __forceinline__ void copy_half(const f16* lds, f16* __restrict__ gout,
                                          int ldo, int h) {
    const int tid = threadIdx.x;
    #pragma unroll
    for (int ph = 0; ph < 4; ++ph) {
        const int r = ph * 32 + (tid >> 4);
        const int c = (tid & 15) * 8;
        *(f16x8*)(gout + (size_t)(h * 128 + r) * ldo + c) = *(const f16x8*)(lds + r * EPIP + c);
    }
}

// ---- fused z | v^T. 1024 blocks: slab s's 8 consumers share bid%8 (XCD) ----
// bid = (s&7) + 8*ci + 64*(s>>3); ci 0-3: z nt=ci; ci 4-7: vt (ht,lh)
__global__ __launch_bounds__(512, 4) void k_zv8(const f16* __restrict__ x,
                                                const f16* __restrict__ Wzh,
                                                const f16* __restrict__ Wvh,
                                                f16* __restrict__ z,
                                                f16* __restrict__ vt)
{
    __shared__ __align__(16) f16 lds[3 * TUNIT];   // 72KB
    const int bid = blockIdx.x;
    const int s  = (bid & 7) + 8 * (bid >> 6);     // x-slab 0..127 (256 rows)
    const int ci = (bid >> 3) & 7;
    const f16* A; const f16* Bm; f16* gout;
    if (ci < 4) {                                  // z[s rows, nt=ci cols]
        A = x + (size_t)s * 256 * HID;
        Bm = Wzh + (size_t)ci * 128 * HID;
        gout = z + (size_t)s * 256 * HID + ci * 128;
    } else {                                       // vt[h rows, l cols] = Wv @ x^T
        const int ht = (ci - 4) >> 1, lh = (ci - 4) & 1;
        A = Wvh + (size_t)ht * 256 * HID;
        Bm = x + ((size_t)s * 256 + lh * 128) * HID;
        gout = vt + (size_t)(s >> 1) * LEN * HID + (size_t)ht * 256 * LEN
                  + (s & 1) * 256 + lh * 128;
    }
    f32x4 acc[4][4];
    gemm8b(A, Bm, HID / 32, lds, acc);
    __syncthreads();
    EPI_IDX();
    #pragma unroll
    for (int h = 0; h < 2; ++h) {
        if ((wr >> 1) == h) {
            const int rb = (wr & 1) * 64;
            #pragma unroll
            for (int m = 0; m < 4; ++m)
                #pragma unroll
                for (int n = 0; n < 4; ++n)
                    #pragma unroll
                    for (int i = 0; i < 4; ++i)
                        lds[(rb + m * 16 + r0 + i) * EPIP + wc * 64 + n * 16 + c0] =
                            (f16)silu_f(acc[m][n][i]);
        }
        __syncthreads();
        copy_half(lds, gout, 512, h);
        __syncthreads();
    }
}

// ---- fused q | k projections, same structure over z-slabs ----
__global__ __launch_bounds__(512, 4) void k_qkp8(const f16* __restrict__ z,
                                                 const f16* __restrict__ Wqh,
                                                 const f16* __restrict__ Wkh,
                                                 const float* __restrict__ gq,
                                                 const float* __restrict__ bq,
                                                 const float* __restrict__ gk,
                                                 const float* __restrict__ bk,
                                                 f16* __restrict__ qh,
                                                 f16* __restrict__ kh)
{
    __shared__ __align__(16) f16 lds[3 * TUNIT];
    const int bid = blockIdx.x;
    const int s  = (bid & 7) + 8 * (bid >> 6);
    const int ci = (bid >> 3) & 7;
    const bool isq = ci < 4;
    const int nt = ci & 3;
    const f16* W = isq ? Wqh : Wkh;
    const float* g  = isq ? gq : gk;
    const float* be = isq ? bq : bk;
    f16* outp = isq ? qh : kh;
    f32x4 acc[4][4];
    gemm8b(z + (size_t)s * 256 * HID, W + (size_t)nt * 128 * HID, HID / 32, lds, acc);
    __syncthreads();
    EPI_IDX();
    f16* gbase = outp + (size_t)s * 256 * HID + nt * 128;
    #pragma unroll
    for (int h = 0; h < 2; ++h) {
        if ((wr >> 1) == h) {
            const int rb = (wr & 1) * 64;
            #pragma unroll
            for (int n = 0; n < 4; ++n) {
                const int col = wc * 64 + n * 16 + c0;
                const int jg = nt * 128 + col;
                const float ga = g[jg], ba = be[jg];
                #pragma unroll
                for (int m = 0; m < 4; ++m)
                    #pragma unroll
                    for (int i = 0; i < 4; ++i)
                        lds[(rb + m * 16 + r0 + i) * EPIP + col] =
                            (f16)((acc[m][n][i] * ga + ba) * 1024.f);
            }
        }
        __syncthreads();
        copy_half(lds, gbase, 512, h);
        __syncthreads();
    }
}

// ---- batched q@k^T + mask + smask + relu^2 -> p. 6 tri-tiles (256x128) ----
// 384 blocks: bid = (b&7) + 8*(t + 6*(b>>3))
__constant__ int LT6[6] = {0,0,1,1,1,1};
__constant__ int MT6[6] = {0,1,0,1,2,3};

__global__ __launch_bounds__(512, 4) void k_qk8(const f16* __restrict__ q,
                                                const f16* __restrict__ kmat,
                                                const int* __restrict__ mask,
                                                const float* __restrict__ smask,
                                                f16* __restrict__ p)
{
    __shared__ __align__(16) f16 lds[3 * TUNIT];
    const int bid = blockIdx.x;
    const int t = (bid >> 3) % 6;
    const int b = (bid & 7) + 8 * (bid / 48);
    const int lt = LT6[t], mt = MT6[t];
    const size_t boff = (size_t)b * LEN * HID;
    f32x4 acc[4][4];
    gemm8b(q + boff + (size_t)lt * 256 * HID,
           kmat + boff + (size_t)mt * 128 * HID, HID / 32, lds, acc);
    __syncthreads();
    EPI_IDX();
    f16* gbase = p + (size_t)b * LEN * LEN + (size_t)lt * 256 * LEN + mt * 128;
    #pragma unroll
    for (int h = 0; h < 2; ++h) {
        if ((wr >> 1) == h) {
            const int rb = (wr & 1) * 64;
            #pragma unroll
            for (int n = 0; n < 4; ++n) {
                const int col = wc * 64 + n * 16 + c0;
                const int m_g = mt * 128 + col;
                const int keepcol = mask[b * LEN + m_g];
                #pragma unroll
                for (int m = 0; m < 4; ++m)
                    #pragma unroll
                    for (int i = 0; i < 4; ++i) {
                        const int row = rb + m * 16 + r0 + i;
                        const int l_g = lt * 256 + h * 128 + row;
                        const bool keep = (l_g == m_g) || ((m_g <= l_g) && (keepcol != 0));
                        float v = keep ? acc[m][n][i] * smask[l_g * LEN + m_g] : 0.f;
                        v = fmaxf(v, 0.f);
                        lds[row * EPIP + col] = (f16)(v * v);
                    }
            }
        }
        __syncthreads();
        copy_half(lds, gbase, 512, h);
        __syncthreads();
    }
}

// ---- batched p@v -> out f32; causal K truncation; long lt first ----
// 512 blocks: bid = (b&7) + 8*(inner + 8*(b>>3)); inner = (1-lt)*4 + ht
__global__ __launch_bounds__(512, 4) void k_pv8(const f16* __restrict__ p,
                                                const f16* __restrict__ vt,
                                                float* __restrict__ out)
{
    __shared__ __align__(16) f16 lds[3 * TUNIT];
    const int bid = blockIdx.x;
    const int inner = (bid >> 3) & 7;
    const int b = (bid & 7) + 8 * (bid >> 6);
    const int lt = 1 - (inner >> 2), ht = inner & 3;
    f32x4 acc[4][4];
    gemm8b(p + (size_t)b * LEN * LEN + (size_t)lt * 256 * LEN,
           vt + (size_t)b * HID * LEN + (size_t)ht * 128 * LEN,
           (lt + 1) * 8, lds, acc);
    EPI_IDX();
    // undo q,k 2^10 lifts (squared -> 2^40) and /(L*H)=2^18 : 2^-58 exact
    const float SCALE = 3.4694469519536142e-18f;
    #pragma unroll
    for (int m = 0; m < 4; ++m)
        #pragma unroll
        for (int n = 0; n < 4; ++n) {
            const int h = ht * 128 + wc * 64 + n * 16 + c0;
            #pragma unroll
            for (int i = 0; i < 4; ++i) {
                const int l = lt * 256 + wr * 64 + m * 16 + r0 + i;
                out[(size_t)b * LEN * HID + (size_t)l * HID + h] = acc[m][n][i] * SCALE;
            }
        }
}

// ---- one prep launch: gather(x) + 4x weight f2h + smask ----
__global__ __launch_bounds__(256) void k_prep(const int* __restrict__ pos,
                                              const float* __restrict__ item_emb,
                                              const float* __restrict__ pos_emb,
                                              f16* __restrict__ x,
                                              const float* __restrict__ Wz,
                                              const float* __restrict__ Wv,
                                              const float* __restrict__ Wq,
                                              const float* __restrict__ Wk,
                                              f16* __restrict__ Wzh,
                                              f16* __restrict__ Wvh,
                                              f16* __restrict__ Wqh,
                                              f16* __restrict__ Wkh,
                                              const float* __restrict__ sw,
                                              const float* __restrict__ gum,
                                              float* __restrict__ smask)
{
    const int bid = blockIdx.x;
    const int tid = threadIdx.x;
    if (bid < 16384) {                       // gather: x = item_emb[pos] + pos_emb
        const int t = bid * 256 + tid;
        const int i = t >> 7;
        const int c = t & 127;
        const int l = i & (LEN - 1);
        const int item = pos[i];
        const float4 a  = ((const float4*)(item_emb + (size_t)item * HID))[c];
        const float4 b4 = ((const float4*)(pos_emb + (size_t)l * HID))[c];
        f16x4 o = { (f16)(a.x + b4.x), (f16)(a.y + b4.y),
                    (f16)(a.z + b4.z), (f16)(a.w + b4.w) };
        *(f16x4*)(x + (size_t)t * 4) = o;
    } else if (bid < 16384 + 1024) {         // weight f32 -> f16
        const int r = bid - 16384;
        const int w = r >> 8;
        const float* s = (w == 0) ? Wz : (w == 1) ? Wv : (w == 2) ? Wq : Wk;
        f16* d = (w == 0) ? Wzh : (w == 1) ? Wvh : (w == 2) ? Wqh : Wkh;
        const int t = (r & 255) * 256 + tid;
        const float4 v = ((const float4*)s)[t];
        f16x4 o = { (f16)v.x, (f16)v.y, (f16)v.z, (f16)v.w };
        *(f16x4*)(d + (size_t)t * 4) = o;
    } else {                                 // gumbel-sigmoid smask (fp32)
        const int t = (bid - 16384 - 1024) * 256 + tid;
        const float4 w4 = ((const float4*)sw)[t];
        const float4 g4 = ((const float4*)gum)[t];
        float4 o;
        o.x = __builtin_amdgcn_rcpf(1.f + __expf(-(__logf(w4.x / (1.f - w4.x)) + g4.x) * 5.f));
        o.y = __builtin_amdgcn_rcpf(1.f + __expf(-(__logf(w4.y / (1.f - w4.y)) + g4.y) * 5.f));
        o.z = __builtin_amdgcn_rcpf(1.f + __expf(-(__logf(w4.z / (1.f - w4.z)) + g4.z) * 5.f));
        o.w = __builtin_amdgcn_rcpf(1.f + __expf(-(__logf(w4.w / (1.f - w4.w)) + g4.w) * 5.f));
        ((float4*)smask)[t] = o;
    }
}

extern "C" void kernel_launch(void* const* d_in, const int* in_sizes, int n_in,
                              void* d_out, int out_size, void* d_ws, size_t ws_size,
                              hipStream_t stream)
{
    const int*   positives = (const int*)  d_in[0];
    const int*   mask      = (const int*)  d_in[1];
    const float* item_emb  = (const float*)d_in[2];
    const float* pos_emb   = (const float*)d_in[3];
    const float* Wz        = (const float*)d_in[4];
    const float* Wv        = (const float*)d_in[5];
    const float* Wq        = (const float*)d_in[6];
    const float* Wk        = (const float*)d_in[7];
    const float* gamma_q   = (const float*)d_in[8];
    const float* beta_q    = (const float*)d_in[9];
    const float* gamma_k   = (const float*)d_in[10];
    const float* beta_k    = (const float*)d_in[11];
    const float* sparse_w  = (const float*)d_in[12];
    const float* gumbel    = (const float*)d_in[13];
    float* out = (float*)d_out;

    char* ws = (char*)d_ws;
    const size_t BUFB = (size_t)BATCH * LEN * HID * sizeof(f16);  // 32 MB
    f16* buf0 = (f16*)ws;                // x  -> p
    f16* buf1 = (f16*)(ws + BUFB);       // z
    f16* buf2 = (f16*)(ws + 2 * BUFB);   // vt
    f16* Wzh  = (f16*)(ws + 3 * BUFB);
    f16* Wvh  = Wzh + LEN * HID;
    f16* Wqh  = Wvh + LEN * HID;
    f16* Wkh  = Wqh + LEN * HID;
    float* smask = (float*)(Wkh + LEN * HID);
    // q,k live in d_out (exactly 2 x 32MB fp16) until k_pv overwrites it
    f16* qh = (f16*)d_out;
    f16* kh = qh + (size_t)BATCH * LEN * HID;

    k_prep<<<16384 + 1024 + 256, 256, 0, stream>>>(
        positives, item_emb, pos_emb, buf0,
        Wz, Wv, Wq, Wk, Wzh, Wvh, Wqh, Wkh,
        sparse_w, gumbel, smask);

    k_zv8<<<1024, 512, 0, stream>>>(buf0, Wzh, Wvh, buf1, buf2);

    k_qkp8<<<1024, 512, 0, stream>>>(buf1, Wqh, Wkh,
                                     gamma_q, beta_q, gamma_k, beta_k, qh, kh);

    k_qk8<<<384, 512, 0, stream>>>(qh, kh, mask, smask, buf0);

    k_pv8<<<512, 512, 0, stream>>>(buf0, buf2, out);
}